// Round 1
// baseline (39.936 us; speedup 1.0000x reference)
//
#include <hip/hip_runtime.h>

// Problem: B=4, C=1024, H=16, D=64.
// Reference broadcasts x along the sequence axis, so q/k/v are constant over
// seq -> softmax(scores) is exactly uniform -> attn@v == v -> final output is
//   out[b] = (x[b] @ Wv + bv) @ Wo + bo        (shape [4,1024], fp32)
// Wq/bq/Wk/bk are mathematically unused (softmax of constant row is uniform).

namespace {

constexpr int CD = 1024;   // C
constexpr int BN = 4;      // B

// Split-K partial matmul: P[kc][b][i] = sum_{c in chunk kc} X[b][c] * W[c][i]
// Grid: 4 output-chunks x NK k-chunks; block = 256 threads (one output col each).
template<int KC>
__global__ __launch_bounds__(256)
void mm_partial(const float* __restrict__ X,   // [4][1024]
                const float* __restrict__ W,   // [1024][1024] row-major [in][out]
                float* __restrict__ P)         // [NK][4][1024]
{
    const int tid = threadIdx.x;
    const int oc  = blockIdx.x & 3;        // output chunk (256 cols)
    const int kc  = blockIdx.x >> 2;       // k chunk
    const int i   = oc * 256 + tid;        // output column
    const int c0  = kc * KC;

    float a0 = 0.f, a1 = 0.f, a2 = 0.f, a3 = 0.f;
#pragma unroll
    for (int cc = 0; cc < KC; ++cc) {
        const int c = c0 + cc;
        const float w = W[c * CD + i];     // coalesced: 256 consecutive floats
        a0 = fmaf(X[0 * CD + c], w, a0);   // X[c] block-uniform -> scalar loads
        a1 = fmaf(X[1 * CD + c], w, a1);
        a2 = fmaf(X[2 * CD + c], w, a2);
        a3 = fmaf(X[3 * CD + c], w, a3);
    }
    float* Pk = P + (size_t)kc * (BN * CD);
    Pk[0 * CD + i] = a0;
    Pk[1 * CD + i] = a1;
    Pk[2 * CD + i] = a2;
    Pk[3 * CD + i] = a3;
}

// Y[b][i] = sum_kc P[kc][b][i] + bias[i]
template<int NK>
__global__ __launch_bounds__(256)
void reduce_bias(const float* __restrict__ P,    // [NK][4][1024]
                 const float* __restrict__ bias, // [1024]
                 float* __restrict__ Y)          // [4][1024]
{
    const int idx = blockIdx.x * 256 + threadIdx.x;  // 0..4095
    const int i   = idx & (CD - 1);
    float s = bias[i];
#pragma unroll
    for (int kc = 0; kc < NK; ++kc)
        s += P[kc * (BN * CD) + idx];
    Y[idx] = s;
}

template<int NK>
void run(const float* x, const float* Wv, const float* bv,
         const float* Wo, const float* bo,
         float* out, float* ws, hipStream_t stream)
{
    constexpr int KC = CD / NK;
    float* t = ws;               // [4][1024] intermediate (x@Wv+bv)
    float* P = ws + BN * CD;     // [NK][4][1024] partials (reused for both legs)

    mm_partial<KC><<<4 * NK, 256, 0, stream>>>(x, Wv, P);
    reduce_bias<NK><<<(BN * CD) / 256, 256, 0, stream>>>(P, bv, t);
    mm_partial<KC><<<4 * NK, 256, 0, stream>>>(t, Wo, P);
    reduce_bias<NK><<<(BN * CD) / 256, 256, 0, stream>>>(P, bo, out);
}

} // namespace

extern "C" void kernel_launch(void* const* d_in, const int* in_sizes, int n_in,
                              void* d_out, int out_size, void* d_ws, size_t ws_size,
                              hipStream_t stream)
{
    // setup_inputs() order: x, Wq, bq, Wk, bk, Wv, bv, Wo, bo  (all fp32)
    const float* x  = (const float*)d_in[0];
    const float* Wv = (const float*)d_in[5];
    const float* bv = (const float*)d_in[6];
    const float* Wo = (const float*)d_in[7];
    const float* bo = (const float*)d_in[8];
    float* out = (float*)d_out;
    float* ws  = (float*)d_ws;

    // Workspace need: (1 + NK) * 4096 floats. Fall back to smaller split-K if
    // the scratch buffer is unexpectedly small.
    const size_t need64 = (size_t)(1 + 64) * BN * CD * sizeof(float);
    const size_t need16 = (size_t)(1 + 16) * BN * CD * sizeof(float);
    if (ws_size >= need64) {
        run<64>(x, Wv, bv, Wo, bo, out, ws, stream);
    } else if (ws_size >= need16) {
        run<16>(x, Wv, bv, Wo, bo, out, ws, stream);
    } else {
        run<4>(x, Wv, bv, Wo, bo, out, ws, stream);
    }
}

// Round 2
// 13.795 us; speedup vs baseline: 2.8949x; 2.8949x over previous
//
#include <hip/hip_runtime.h>

// Problem: B=4, C=1024, H=16, D=64.
// Reference broadcasts x along the sequence axis, so q/k/v are constant over
// seq -> softmax(scores) is exactly uniform -> attn@v == v -> output is
//   out[b] = (x[b] @ Wv + bv) @ Wo + bo        (shape [4,1024], fp32)
// Wq/bq/Wk/bk are mathematically unused.
//
// Two fused matvec+bias kernels (one per leg); split-K handled INSIDE the
// block via LDS tree-reduce (no partial buffer, no reduce kernel).

namespace {

constexpr int CD   = 1024;  // C
constexpr int BN   = 4;     // B
constexpr int COLS = 8;     // output columns per block
constexpr int KS   = 32;    // k-slices per block (threads = COLS*KS = 256)
constexpr int KC   = CD / KS; // 32 k-elements per slice

// Y[b][i] = sum_c X[b][c] * W[c][i] + bias[i]
__global__ __launch_bounds__(256)
void matvec_leg(const float* __restrict__ X,    // [4][1024]
                const float* __restrict__ W,    // [1024][1024] ([in][out])
                const float* __restrict__ bias, // [1024]
                float* __restrict__ Y)          // [4][1024]
{
    __shared__ float xs[BN * CD];       // 16 KB: whole X
    __shared__ float red[256 * BN];     // 4 KB: per-thread float4 partials

    const int tid = threadIdx.x;

    // Stage X into LDS (coalesced float4: 4 iters x 256 threads x 16 B).
    {
        const float4* Xv = (const float4*)X;
        float4* xsv = (float4*)xs;
#pragma unroll
        for (int k = 0; k < (BN * CD / 4) / 256; ++k)
            xsv[k * 256 + tid] = Xv[k * 256 + tid];
    }
    __syncthreads();

    const int col = tid & (COLS - 1);   // 0..7
    const int ks  = tid / COLS;         // 0..31
    const int i   = blockIdx.x * COLS + col;

    // Interleaved K-walk: c = cc*KS + ks.
    //  - xs read: 8 ks-groups of a wave hit 8 CONSECUTIVE floats -> no bank
    //    conflict (each is an 8-lane broadcast).
    //  - W read: per ks-group 8 consecutive floats (32 B segment), coalesced.
    float a0 = 0.f, a1 = 0.f, a2 = 0.f, a3 = 0.f;
#pragma unroll
    for (int cc = 0; cc < KC; ++cc) {
        const int c = cc * KS + ks;
        const float w = W[c * CD + i];
        a0 = fmaf(xs[0 * CD + c], w, a0);
        a1 = fmaf(xs[1 * CD + c], w, a1);
        a2 = fmaf(xs[2 * CD + c], w, a2);
        a3 = fmaf(xs[3 * CD + c], w, a3);
    }

    // LDS tree-reduce over ks (red4 indexed [ks][col]).
    float4* r4 = (float4*)red;
    r4[tid] = make_float4(a0, a1, a2, a3);
    __syncthreads();
#pragma unroll
    for (int s = KS / 2; s >= 1; s >>= 1) {
        if (ks < s) {
            float4 o = r4[tid + s * COLS];
            float4 m = r4[tid];
            m.x += o.x; m.y += o.y; m.z += o.z; m.w += o.w;
            r4[tid] = m;
        }
        __syncthreads();
    }

    // red4[col] now holds the 4-batch result for column (blk*COLS+col).
    if (tid < COLS * BN) {
        const int c2 = tid >> 2;        // column 0..7
        const int b  = tid & 3;         // batch 0..3
        const int ii = blockIdx.x * COLS + c2;
        Y[b * CD + ii] = red[c2 * 4 + b] + bias[ii];
    }
}

} // namespace

extern "C" void kernel_launch(void* const* d_in, const int* in_sizes, int n_in,
                              void* d_out, int out_size, void* d_ws, size_t ws_size,
                              hipStream_t stream)
{
    // setup_inputs() order: x, Wq, bq, Wk, bk, Wv, bv, Wo, bo  (all fp32)
    const float* x  = (const float*)d_in[0];
    const float* Wv = (const float*)d_in[5];
    const float* bv = (const float*)d_in[6];
    const float* Wo = (const float*)d_in[7];
    const float* bo = (const float*)d_in[8];
    float* out = (float*)d_out;
    float* t   = (float*)d_ws;          // [4][1024] intermediate (16 KB)

    matvec_leg<<<CD / COLS, 256, 0, stream>>>(x, Wv, bv, t);
    matvec_leg<<<CD / COLS, 256, 0, stream>>>(t, Wo, bo, out);
}